// Round 1
// baseline (656.165 us; speedup 1.0000x reference)
//
#include <hip/hip_runtime.h>

#define IN_H 256
#define IN_W 256
#define C0   3
#define C1   32
#define H1   128
#define C2   64
#define H2   64
#define NB   32
#define K_FLAT (H2*H2*C2)   // 262144
#define NHID 128

// ---------------------------------------------------------------- conv1
// in [32,256,256,3] -> a1 [32,128,128,32], stride2 SAME (pad_lo=0, pad_hi=1), ReLU
__global__ __launch_bounds__(128)
void conv1_k(const float* __restrict__ in, const float* __restrict__ k1,
             const float* __restrict__ b1, float* __restrict__ a1) {
  const int ox = threadIdx.x;      // 0..127
  const int oy = blockIdx.x;       // 0..127
  const int b  = blockIdx.y;       // 0..31
  float acc[C1];
#pragma unroll
  for (int co = 0; co < C1; ++co) acc[co] = b1[co];

  for (int dy = 0; dy < 3; ++dy) {
    const int iy  = 2*oy + dy;
    const bool rok = iy < IN_H;
    const int iyc = rok ? iy : (IN_H-1);
    for (int dx = 0; dx < 3; ++dx) {
      const int ix  = 2*ox + dx;
      const bool ok = rok && (ix < IN_W);
      const int ixc = (ix < IN_W) ? ix : (IN_W-1);
      const float* ip = in + ((size_t)(b*IN_H + iyc)*IN_W + ixc)*C0;
      const float v0 = ok ? ip[0] : 0.f;
      const float v1 = ok ? ip[1] : 0.f;
      const float v2 = ok ? ip[2] : 0.f;
      const float* wp = k1 + (size_t)((dy*3+dx)*C0)*C1;   // [ci][co], co contiguous
#pragma unroll
      for (int co = 0; co < C1; ++co)
        acc[co] = fmaf(v0, wp[co],
                  fmaf(v1, wp[C1+co],
                  fmaf(v2, wp[2*C1+co], acc[co])));
    }
  }
  float* op = a1 + ((size_t)(b*H1 + oy)*H1 + ox)*C1;
#pragma unroll
  for (int g = 0; g < 8; ++g) {
    float4 o;
    o.x = fmaxf(acc[4*g+0], 0.f);
    o.y = fmaxf(acc[4*g+1], 0.f);
    o.z = fmaxf(acc[4*g+2], 0.f);
    o.w = fmaxf(acc[4*g+3], 0.f);
    ((float4*)op)[g] = o;
  }
}

// ---------------------------------------------------------------- conv2
// a1 [32,128,128,32] -> a2 [32,64,64,64], stride2 SAME, ReLU
__global__ __launch_bounds__(256)
void conv2_k(const float* __restrict__ a1, const float* __restrict__ k2,
             const float* __restrict__ b2, float* __restrict__ a2) {
  const int tid = threadIdx.x;
  const int ox  = tid & 63;                    // 0..63
  const int oy  = blockIdx.x*4 + (tid >> 6);   // 4 rows per block
  const int b   = blockIdx.y;
  float acc[C2];
#pragma unroll
  for (int co = 0; co < C2; ++co) acc[co] = b2[co];

  for (int dy = 0; dy < 3; ++dy) {
    const int iy  = 2*oy + dy;
    const bool rok = iy < H1;
    const int iyc = rok ? iy : (H1-1);
    for (int dx = 0; dx < 3; ++dx) {
      const int ix  = 2*ox + dx;
      const bool ok = rok && (ix < H1);
      const int ixc = (ix < H1) ? ix : (H1-1);
      const float4* ip = (const float4*)(a1 + ((size_t)(b*H1 + iyc)*H1 + ixc)*C1);
      float4 v4[8];
#pragma unroll
      for (int g = 0; g < 8; ++g) {
        float4 t = ip[g];
        v4[g] = ok ? t : make_float4(0.f,0.f,0.f,0.f);
      }
      const float* wp = k2 + (size_t)((dy*3+dx)*C1)*C2;   // [ci][co], co contiguous
#pragma unroll
      for (int g = 0; g < 8; ++g) {
#pragma unroll
        for (int cc = 0; cc < 4; ++cc) {
          const float vv = (cc==0) ? v4[g].x : (cc==1) ? v4[g].y : (cc==2) ? v4[g].z : v4[g].w;
          const float* wr = wp + (size_t)(g*4+cc)*C2;
#pragma unroll
          for (int co = 0; co < C2; ++co) acc[co] = fmaf(vv, wr[co], acc[co]);
        }
      }
    }
  }
  float* op = a2 + ((size_t)(b*H2 + oy)*H2 + ox)*C2;
#pragma unroll
  for (int g = 0; g < 16; ++g) {
    float4 o;
    o.x = fmaxf(acc[4*g+0], 0.f);
    o.y = fmaxf(acc[4*g+1], 0.f);
    o.z = fmaxf(acc[4*g+2], 0.f);
    o.w = fmaxf(acc[4*g+3], 0.f);
    ((float4*)op)[g] = o;
  }
}

// ---------------------------------------------------------------- FC1 partial
// x = a2 flattened [32, 262144]; w1 [262144, 128]. Each block owns a 1024-k span,
// stages 256-k chunks of x transposed in LDS (pad 36 => 16B-aligned rows, b128 reads),
// accumulates a [32 b x 4 n] fp32 tile per thread. kk (tid>>5) splits k 8-way;
// reduced in LDS, then 32 lanes write the block partial.
#define FC1_G   256
#define KSPAN   (K_FLAT / FC1_G)   // 1024
#define KCH     256

#define FMA4(A, s) do { (A).x = fmaf((s),(w4).x,(A).x); (A).y = fmaf((s),(w4).y,(A).y); \
                        (A).z = fmaf((s),(w4).z,(A).z); (A).w = fmaf((s),(w4).w,(A).w); } while(0)

__global__ __launch_bounds__(256)
void fc1_partial_k(const float* __restrict__ a2, const float* __restrict__ w1,
                   float* __restrict__ partial) {
  __shared__ __align__(16) float xT[KCH*36];   // 36,864 B
  const int tid = threadIdx.x;
  const int q   = tid & 31;    // n-quad: n = 4q..4q+3
  const int kk  = tid >> 5;    // 0..7
  const int kbase = blockIdx.x * KSPAN;
  const int lb  = tid >> 3;    // staging b 0..31
  const int lkq = tid & 7;     // staging k-octant

  float4 acc[32];
#pragma unroll
  for (int i = 0; i < 32; ++i) acc[i] = make_float4(0.f,0.f,0.f,0.f);

  for (int c = 0; c < KSPAN/KCH; ++c) {   // 4 chunks
    const int k0 = kbase + c*KCH;
    __syncthreads();
    // stage x chunk transposed: xT[k][b]
#pragma unroll
    for (int j = 0; j < 8; ++j) {
      const int k4 = lkq*4 + j*32;
      float4 t = *(const float4*)(a2 + (size_t)lb*K_FLAT + k0 + k4);
      xT[(k4+0)*36 + lb] = t.x;
      xT[(k4+1)*36 + lb] = t.y;
      xT[(k4+2)*36 + lb] = t.z;
      xT[(k4+3)*36 + lb] = t.w;
    }
    __syncthreads();
    // compute: per j, 1 coalesced w1 float4 + 8 LDS b128 + 128 FMA
    for (int j = 0; j < KCH/8; ++j) {
      const int k = kk + j*8;
      const float4 w4 = *(const float4*)(w1 + (size_t)(k0 + k)*NHID + 4*q);
#pragma unroll
      for (int i = 0; i < 8; ++i) {
        const float4 xb = *(const float4*)&xT[k*36 + 4*i];
        FMA4(acc[4*i+0], xb.x);
        FMA4(acc[4*i+1], xb.y);
        FMA4(acc[4*i+2], xb.z);
        FMA4(acc[4*i+3], xb.w);
      }
    }
  }

  // reduce the 8 kk groups (sequential rounds through LDS; once per block)
  float4* lds4 = (float4*)xT;
  for (int r = 1; r < 8; ++r) {
    __syncthreads();
    if (kk == r) {
#pragma unroll
      for (int i = 0; i < 32; ++i) lds4[q*32 + i] = acc[i];
    }
    __syncthreads();
    if (kk == 0) {
#pragma unroll
      for (int i = 0; i < 32; ++i) {
        const float4 t = lds4[q*32 + i];
        acc[i].x += t.x; acc[i].y += t.y; acc[i].z += t.z; acc[i].w += t.w;
      }
    }
  }
  if (kk == 0) {
    float* pp = partial + (size_t)blockIdx.x*(NB*NHID);
#pragma unroll
    for (int i = 0; i < 32; ++i)             // i = b
      *(float4*)(pp + i*NHID + 4*q) = acc[i];
  }
}

// ---------------------------------------------------------------- FC1 reduce (+bias+ReLU)
__global__ __launch_bounds__(128)
void fc1_reduce_k(const float* __restrict__ partial, const float* __restrict__ d1,
                  float* __restrict__ h) {
  const int t = blockIdx.x*128 + threadIdx.x;  // 0..4095 : b = t>>7, n = t&127
  float s = 0.f;
#pragma unroll 8
  for (int g = 0; g < FC1_G; ++g) s += partial[(size_t)g*(NB*NHID) + t];
  h[t] = fmaxf(s + d1[t & (NHID-1)], 0.f);
}

// ---------------------------------------------------------------- theta = relu(h) @ w2 + d2
__global__ __launch_bounds__(192)
void theta_k(const float* __restrict__ h, const float* __restrict__ w2,
             const float* __restrict__ d2, float* __restrict__ theta) {
  const int t = threadIdx.x;
  if (t >= NB*6) return;
  const int b = t / 6, j = t % 6;
  float s = d2[j];
  for (int n = 0; n < NHID; ++n) s = fmaf(h[b*NHID + n], w2[n*6 + j], s);
  theta[t] = s;
}

// ---------------------------------------------------------------- grid sample (bilinear, zero pad)
__global__ __launch_bounds__(256)
void sample_k(const float* __restrict__ img, const float* __restrict__ theta,
              float* __restrict__ out) {
  const int x = threadIdx.x;
  const int y = blockIdx.x & (IN_H-1);
  const int b = blockIdx.x >> 8;
  const float* tp = theta + b*6;
  const float t0 = tp[0], t1 = tp[1], t2 = tp[2];
  const float t3 = tp[3], t4 = tp[4], t5 = tp[5];

  const float xs = (2.f*x + 1.f)*(1.f/IN_W) - 1.f;
  const float ys = (2.f*y + 1.f)*(1.f/IN_H) - 1.f;
  const float gx = fmaf(t0, xs, fmaf(t1, ys, t2));
  const float gy = fmaf(t3, xs, fmaf(t4, ys, t5));
  const float px = fmaf(gx + 1.f, 0.5f*IN_W, -0.5f);
  const float py = fmaf(gy + 1.f, 0.5f*IN_H, -0.5f);

  const float x0f = floorf(px), y0f = floorf(py);
  const int ix0 = (int)x0f, iy0 = (int)y0f;
  const float wx1 = px - x0f, wx0 = 1.f - wx1;
  const float wy1 = py - y0f, wy0 = 1.f - wy1;

  float r = 0.f, g = 0.f, bl = 0.f;
  const float* ib = img + (size_t)b*IN_H*IN_W*C0;

  auto tap = [&](int yi, int xi, float w) {
    const bool v = (xi >= 0) && (xi < IN_W) && (yi >= 0) && (yi < IN_H);
    const int xc = xi < 0 ? 0 : (xi > IN_W-1 ? IN_W-1 : xi);
    const int yc = yi < 0 ? 0 : (yi > IN_H-1 ? IN_H-1 : yi);
    const float* p = ib + ((size_t)yc*IN_W + xc)*C0;
    if (v) {
      r  = fmaf(w, p[0], r);
      g  = fmaf(w, p[1], g);
      bl = fmaf(w, p[2], bl);
    }
  };
  tap(iy0,   ix0,   wy0*wx0);
  tap(iy0,   ix0+1, wy0*wx1);
  tap(iy0+1, ix0,   wy1*wx0);
  tap(iy0+1, ix0+1, wy1*wx1);

  float* op = out + ((size_t)(b*IN_H + y)*IN_W + x)*C0;
  op[0] = r; op[1] = g; op[2] = bl;
}

// ---------------------------------------------------------------- launch
extern "C" void kernel_launch(void* const* d_in, const int* in_sizes, int n_in,
                              void* d_out, int out_size, void* d_ws, size_t ws_size,
                              hipStream_t stream) {
  const float* in = (const float*)d_in[0];
  const float* k1 = (const float*)d_in[1];
  const float* b1 = (const float*)d_in[2];
  const float* k2 = (const float*)d_in[3];
  const float* b2 = (const float*)d_in[4];
  const float* w1 = (const float*)d_in[5];
  const float* d1 = (const float*)d_in[6];
  const float* w2 = (const float*)d_in[7];
  const float* d2 = (const float*)d_in[8];
  float* out = (float*)d_out;
  float* ws  = (float*)d_ws;

  // ws layout (floats):
  //   a1      [32*128*128*32] @ 0          (16,777,216)
  //   a2      [32*64*64*64]   @ 16,777,216 ( 8,388,608)  -> ws end ~100.7 MB
  //   partial [256*32*128]    @ 0          (reuses dead a1; 1,048,576)
  //   h       [32*128]        @ 1,048,576
  //   theta   [32*6]          @ 1,052,672
  float* a1      = ws;
  float* a2      = ws + (size_t)16777216;
  float* partial = ws;
  float* h       = ws + (size_t)1048576;
  float* th      = ws + (size_t)1048576 + 4096;

  hipLaunchKernelGGL(conv1_k,      dim3(128, 32), dim3(128), 0, stream, in, k1, b1, a1);
  hipLaunchKernelGGL(conv2_k,      dim3(16, 32),  dim3(256), 0, stream, a1, k2, b2, a2);
  hipLaunchKernelGGL(fc1_partial_k,dim3(FC1_G),   dim3(256), 0, stream, a2, w1, partial);
  hipLaunchKernelGGL(fc1_reduce_k, dim3(32),      dim3(128), 0, stream, partial, d1, h);
  hipLaunchKernelGGL(theta_k,      dim3(1),       dim3(192), 0, stream, h, w2, d2, th);
  hipLaunchKernelGGL(sample_k,     dim3(NB*IN_H), dim3(256), 0, stream, in, th, out);
}

// Round 2
// 618.937 us; speedup vs baseline: 1.0601x; 1.0601x over previous
//
#include <hip/hip_runtime.h>

#define IN_H 256
#define IN_W 256
#define C0   3
#define C1   32
#define H1   128
#define C2   64
#define H2   64
#define NB   32
#define K_FLAT (H2*H2*C2)   // 262144
#define NHID 128

// ---------------------------------------------------------------- conv1
// in [32,256,256,3] -> a1 [32,128,128,32], stride2 SAME (pad_lo=0, pad_hi=1), ReLU
__global__ __launch_bounds__(128)
void conv1_k(const float* __restrict__ in, const float* __restrict__ k1,
             const float* __restrict__ b1, float* __restrict__ a1) {
  const int ox = threadIdx.x;      // 0..127
  const int oy = blockIdx.x;       // 0..127
  const int b  = blockIdx.y;       // 0..31
  float acc[C1];
#pragma unroll
  for (int co = 0; co < C1; ++co) acc[co] = b1[co];

  for (int dy = 0; dy < 3; ++dy) {
    const int iy  = 2*oy + dy;
    const bool rok = iy < IN_H;
    const int iyc = rok ? iy : (IN_H-1);
    for (int dx = 0; dx < 3; ++dx) {
      const int ix  = 2*ox + dx;
      const bool ok = rok && (ix < IN_W);
      const int ixc = (ix < IN_W) ? ix : (IN_W-1);
      const float* ip = in + ((size_t)(b*IN_H + iyc)*IN_W + ixc)*C0;
      const float v0 = ok ? ip[0] : 0.f;
      const float v1 = ok ? ip[1] : 0.f;
      const float v2 = ok ? ip[2] : 0.f;
      const float* wp = k1 + (size_t)((dy*3+dx)*C0)*C1;   // [ci][co], co contiguous
#pragma unroll
      for (int co = 0; co < C1; ++co)
        acc[co] = fmaf(v0, wp[co],
                  fmaf(v1, wp[C1+co],
                  fmaf(v2, wp[2*C1+co], acc[co])));
    }
  }
  float* op = a1 + ((size_t)(b*H1 + oy)*H1 + ox)*C1;
#pragma unroll
  for (int g = 0; g < 8; ++g) {
    float4 o;
    o.x = fmaxf(acc[4*g+0], 0.f);
    o.y = fmaxf(acc[4*g+1], 0.f);
    o.z = fmaxf(acc[4*g+2], 0.f);
    o.w = fmaxf(acc[4*g+3], 0.f);
    ((float4*)op)[g] = o;
  }
}

// ---------------------------------------------------------------- conv2
// a1 [32,128,128,32] -> a2 [32,64,64,64], stride2 SAME, ReLU
// __launch_bounds__(256,2): 256-VGPR budget so the 64-float accumulator
// stays in registers (R1: default budget was 60 VGPR -> spilled, 128 MB
// of scratch WRITE traffic, 282 us).
__global__ __launch_bounds__(256, 2)
void conv2_k(const float* __restrict__ a1, const float* __restrict__ k2,
             const float* __restrict__ b2, float* __restrict__ a2) {
  const int tid = threadIdx.x;
  const int ox  = tid & 63;                    // 0..63
  const int oy  = blockIdx.x*4 + (tid >> 6);   // 4 rows per block
  const int b   = blockIdx.y;
  float acc[C2];
#pragma unroll
  for (int co = 0; co < C2; ++co) acc[co] = b2[co];

  for (int dy = 0; dy < 3; ++dy) {
    const int iy  = 2*oy + dy;
    const bool rok = iy < H1;
    const int iyc = rok ? iy : (H1-1);
    for (int dx = 0; dx < 3; ++dx) {
      const int ix  = 2*ox + dx;
      const bool ok = rok && (ix < H1);
      const int ixc = (ix < H1) ? ix : (H1-1);
      const float4* ip = (const float4*)(a1 + ((size_t)(b*H1 + iyc)*H1 + ixc)*C1);
      float4 v4[8];
#pragma unroll
      for (int g = 0; g < 8; ++g) {
        float4 t = ip[g];
        v4[g] = ok ? t : make_float4(0.f,0.f,0.f,0.f);
      }
      const float* wp = k2 + (size_t)((dy*3+dx)*C1)*C2;   // [ci][co], co contiguous
#pragma unroll
      for (int g = 0; g < 8; ++g) {
#pragma unroll
        for (int cc = 0; cc < 4; ++cc) {
          const float vv = (cc==0) ? v4[g].x : (cc==1) ? v4[g].y : (cc==2) ? v4[g].z : v4[g].w;
          const float* wr = wp + (size_t)(g*4+cc)*C2;
#pragma unroll
          for (int co = 0; co < C2; ++co) acc[co] = fmaf(vv, wr[co], acc[co]);
        }
      }
    }
  }
  float* op = a2 + ((size_t)(b*H2 + oy)*H2 + ox)*C2;
#pragma unroll
  for (int g = 0; g < 16; ++g) {
    float4 o;
    o.x = fmaxf(acc[4*g+0], 0.f);
    o.y = fmaxf(acc[4*g+1], 0.f);
    o.z = fmaxf(acc[4*g+2], 0.f);
    o.w = fmaxf(acc[4*g+3], 0.f);
    ((float4*)op)[g] = o;
  }
}

// ---------------------------------------------------------------- FC1 partial
// x = a2 flattened [32, 262144]; w1 [262144, 128]. Each block owns a 512-k span,
// stages 256-k chunks of x transposed in LDS (pad 36 => 16B-aligned rows, b128 reads),
// accumulates a [32 b x 4 n] fp32 tile per thread. kk (tid>>5) splits k 8-way;
// reduced in LDS, then 32 lanes write the block partial.
// FC1_G=512 (R1: 256 blocks = 1 wave/SIMD = zero TLP, latency-bound).
#define FC1_G   512
#define KSPAN   (K_FLAT / FC1_G)   // 512
#define KCH     256

#define FMA4(A, s) do { (A).x = fmaf((s),(w4).x,(A).x); (A).y = fmaf((s),(w4).y,(A).y); \
                        (A).z = fmaf((s),(w4).z,(A).z); (A).w = fmaf((s),(w4).w,(A).w); } while(0)

__global__ __launch_bounds__(256)
void fc1_partial_k(const float* __restrict__ a2, const float* __restrict__ w1,
                   float* __restrict__ partial) {
  __shared__ __align__(16) float xT[KCH*36];   // 36,864 B
  const int tid = threadIdx.x;
  const int q   = tid & 31;    // n-quad: n = 4q..4q+3
  const int kk  = tid >> 5;    // 0..7
  const int kbase = blockIdx.x * KSPAN;
  const int lb  = tid >> 3;    // staging b 0..31
  const int lkq = tid & 7;     // staging k-octant

  float4 acc[32];
#pragma unroll
  for (int i = 0; i < 32; ++i) acc[i] = make_float4(0.f,0.f,0.f,0.f);

  for (int c = 0; c < KSPAN/KCH; ++c) {   // 2 chunks
    const int k0 = kbase + c*KCH;
    __syncthreads();
    // stage x chunk transposed: xT[k][b]
#pragma unroll
    for (int j = 0; j < 8; ++j) {
      const int k4 = lkq*4 + j*32;
      float4 t = *(const float4*)(a2 + (size_t)lb*K_FLAT + k0 + k4);
      xT[(k4+0)*36 + lb] = t.x;
      xT[(k4+1)*36 + lb] = t.y;
      xT[(k4+2)*36 + lb] = t.z;
      xT[(k4+3)*36 + lb] = t.w;
    }
    __syncthreads();
    // compute: per j, 1 coalesced w1 float4 + 8 LDS b128 + 128 FMA
    for (int j = 0; j < KCH/8; ++j) {
      const int k = kk + j*8;
      const float4 w4 = *(const float4*)(w1 + (size_t)(k0 + k)*NHID + 4*q);
#pragma unroll
      for (int i = 0; i < 8; ++i) {
        const float4 xb = *(const float4*)&xT[k*36 + 4*i];
        FMA4(acc[4*i+0], xb.x);
        FMA4(acc[4*i+1], xb.y);
        FMA4(acc[4*i+2], xb.z);
        FMA4(acc[4*i+3], xb.w);
      }
    }
  }

  // reduce the 8 kk groups (sequential rounds through LDS; once per block)
  float4* lds4 = (float4*)xT;
  for (int r = 1; r < 8; ++r) {
    __syncthreads();
    if (kk == r) {
#pragma unroll
      for (int i = 0; i < 32; ++i) lds4[q*32 + i] = acc[i];
    }
    __syncthreads();
    if (kk == 0) {
#pragma unroll
      for (int i = 0; i < 32; ++i) {
        const float4 t = lds4[q*32 + i];
        acc[i].x += t.x; acc[i].y += t.y; acc[i].z += t.z; acc[i].w += t.w;
      }
    }
  }
  if (kk == 0) {
    float* pp = partial + (size_t)blockIdx.x*(NB*NHID);
#pragma unroll
    for (int i = 0; i < 32; ++i)             // i = b
      *(float4*)(pp + i*NHID + 4*q) = acc[i];
  }
}

// ---------------------------------------------------------------- FC1 reduce (+bias+ReLU)
__global__ __launch_bounds__(128)
void fc1_reduce_k(const float* __restrict__ partial, const float* __restrict__ d1,
                  float* __restrict__ h) {
  const int t = blockIdx.x*128 + threadIdx.x;  // 0..4095 : b = t>>7, n = t&127
  float s = 0.f;
#pragma unroll 8
  for (int g = 0; g < FC1_G; ++g) s += partial[(size_t)g*(NB*NHID) + t];
  h[t] = fmaxf(s + d1[t & (NHID-1)], 0.f);
}

// ---------------------------------------------------------------- theta = relu(h) @ w2 + d2
__global__ __launch_bounds__(192)
void theta_k(const float* __restrict__ h, const float* __restrict__ w2,
             const float* __restrict__ d2, float* __restrict__ theta) {
  const int t = threadIdx.x;
  if (t >= NB*6) return;
  const int b = t / 6, j = t % 6;
  float s = d2[j];
  for (int n = 0; n < NHID; ++n) s = fmaf(h[b*NHID + n], w2[n*6 + j], s);
  theta[t] = s;
}

// ---------------------------------------------------------------- grid sample (bilinear, zero pad)
__global__ __launch_bounds__(256)
void sample_k(const float* __restrict__ img, const float* __restrict__ theta,
              float* __restrict__ out) {
  const int x = threadIdx.x;
  const int y = blockIdx.x & (IN_H-1);
  const int b = blockIdx.x >> 8;
  const float* tp = theta + b*6;
  const float t0 = tp[0], t1 = tp[1], t2 = tp[2];
  const float t3 = tp[3], t4 = tp[4], t5 = tp[5];

  const float xs = (2.f*x + 1.f)*(1.f/IN_W) - 1.f;
  const float ys = (2.f*y + 1.f)*(1.f/IN_H) - 1.f;
  const float gx = fmaf(t0, xs, fmaf(t1, ys, t2));
  const float gy = fmaf(t3, xs, fmaf(t4, ys, t5));
  const float px = fmaf(gx + 1.f, 0.5f*IN_W, -0.5f);
  const float py = fmaf(gy + 1.f, 0.5f*IN_H, -0.5f);

  const float x0f = floorf(px), y0f = floorf(py);
  const int ix0 = (int)x0f, iy0 = (int)y0f;
  const float wx1 = px - x0f, wx0 = 1.f - wx1;
  const float wy1 = py - y0f, wy0 = 1.f - wy1;

  float r = 0.f, g = 0.f, bl = 0.f;
  const float* ib = img + (size_t)b*IN_H*IN_W*C0;

  auto tap = [&](int yi, int xi, float w) {
    const bool v = (xi >= 0) && (xi < IN_W) && (yi >= 0) && (yi < IN_H);
    const int xc = xi < 0 ? 0 : (xi > IN_W-1 ? IN_W-1 : xi);
    const int yc = yi < 0 ? 0 : (yi > IN_H-1 ? IN_H-1 : yi);
    const float* p = ib + ((size_t)yc*IN_W + xc)*C0;
    if (v) {
      r  = fmaf(w, p[0], r);
      g  = fmaf(w, p[1], g);
      bl = fmaf(w, p[2], bl);
    }
  };
  tap(iy0,   ix0,   wy0*wx0);
  tap(iy0,   ix0+1, wy0*wx1);
  tap(iy0+1, ix0,   wy1*wx0);
  tap(iy0+1, ix0+1, wy1*wx1);

  float* op = out + ((size_t)(b*IN_H + y)*IN_W + x)*C0;
  op[0] = r; op[1] = g; op[2] = bl;
}

// ---------------------------------------------------------------- launch
extern "C" void kernel_launch(void* const* d_in, const int* in_sizes, int n_in,
                              void* d_out, int out_size, void* d_ws, size_t ws_size,
                              hipStream_t stream) {
  const float* in = (const float*)d_in[0];
  const float* k1 = (const float*)d_in[1];
  const float* b1 = (const float*)d_in[2];
  const float* k2 = (const float*)d_in[3];
  const float* b2 = (const float*)d_in[4];
  const float* w1 = (const float*)d_in[5];
  const float* d1 = (const float*)d_in[6];
  const float* w2 = (const float*)d_in[7];
  const float* d2 = (const float*)d_in[8];
  float* out = (float*)d_out;
  float* ws  = (float*)d_ws;

  // ws layout (floats):
  //   a1      [32*128*128*32] @ 0          (16,777,216)
  //   a2      [32*64*64*64]   @ 16,777,216 ( 8,388,608)  -> ws end ~100.7 MB
  //   partial [512*32*128]    @ 0          (reuses dead a1; 2,097,152)
  //   h       [32*128]        @ 2,097,152
  //   theta   [32*6]          @ 2,101,248
  float* a1      = ws;
  float* a2      = ws + (size_t)16777216;
  float* partial = ws;
  float* h       = ws + (size_t)2097152;
  float* th      = ws + (size_t)2097152 + 4096;

  hipLaunchKernelGGL(conv1_k,      dim3(128, 32), dim3(128), 0, stream, in, k1, b1, a1);
  hipLaunchKernelGGL(conv2_k,      dim3(16, 32),  dim3(256), 0, stream, a1, k2, b2, a2);
  hipLaunchKernelGGL(fc1_partial_k,dim3(FC1_G),   dim3(256), 0, stream, a2, w1, partial);
  hipLaunchKernelGGL(fc1_reduce_k, dim3(32),      dim3(128), 0, stream, partial, d1, h);
  hipLaunchKernelGGL(theta_k,      dim3(1),       dim3(192), 0, stream, h, w2, d2, th);
  hipLaunchKernelGGL(sample_k,     dim3(NB*IN_H), dim3(256), 0, stream, in, th, out);
}

// Round 3
// 404.138 us; speedup vs baseline: 1.6236x; 1.5315x over previous
//
#include <hip/hip_runtime.h>

#define IN_H 256
#define IN_W 256
#define C0   3
#define C1   32
#define H1   128
#define C2   64
#define H2   64
#define NB   32
#define K_FLAT (H2*H2*C2)   // 262144
#define NHID 128

// ---------------------------------------------------------------- conv1
// in [32,256,256,3] -> a1 [32,128,128,32], stride2 SAME (pad_lo=0, pad_hi=1), ReLU
__global__ __launch_bounds__(128)
void conv1_k(const float* __restrict__ in, const float* __restrict__ k1,
             const float* __restrict__ b1, float* __restrict__ a1) {
  const int ox = threadIdx.x;      // 0..127
  const int oy = blockIdx.x;       // 0..127
  const int b  = blockIdx.y;       // 0..31
  float acc[C1];
#pragma unroll
  for (int co = 0; co < C1; ++co) acc[co] = b1[co];

  for (int dy = 0; dy < 3; ++dy) {
    const int iy  = 2*oy + dy;
    const bool rok = iy < IN_H;
    const int iyc = rok ? iy : (IN_H-1);
    for (int dx = 0; dx < 3; ++dx) {
      const int ix  = 2*ox + dx;
      const bool ok = rok && (ix < IN_W);
      const int ixc = (ix < IN_W) ? ix : (IN_W-1);
      const float* ip = in + ((size_t)(b*IN_H + iyc)*IN_W + ixc)*C0;
      const float v0 = ok ? ip[0] : 0.f;
      const float v1 = ok ? ip[1] : 0.f;
      const float v2 = ok ? ip[2] : 0.f;
      const float* wp = k1 + (size_t)((dy*3+dx)*C0)*C1;   // [ci][co], co contiguous
#pragma unroll
      for (int co = 0; co < C1; ++co)
        acc[co] = fmaf(v0, wp[co],
                  fmaf(v1, wp[C1+co],
                  fmaf(v2, wp[2*C1+co], acc[co])));
    }
  }
  float* op = a1 + ((size_t)(b*H1 + oy)*H1 + ox)*C1;
#pragma unroll
  for (int g = 0; g < 8; ++g) {
    float4 o;
    o.x = fmaxf(acc[4*g+0], 0.f);
    o.y = fmaxf(acc[4*g+1], 0.f);
    o.z = fmaxf(acc[4*g+2], 0.f);
    o.w = fmaxf(acc[4*g+3], 0.f);
    ((float4*)op)[g] = o;
  }
}

// ---------------------------------------------------------------- conv2
// a1 [32,128,128,32] -> a2 [32,64,64,64], stride2 SAME, ReLU.
// R2 lesson: allocator pins ~60 VGPR regardless of __launch_bounds__; a
// 64-float acc spills (128 MB scratch writes). Fix structurally: co split
// 4-way across threads -> acc[16]. Block = [cg 4][ox 64]; weight addr is
// wave-uniform via readfirstlane -> s_load + SGPR-operand FMA.
__global__ __launch_bounds__(256)
void conv2_k(const float* __restrict__ a1, const float* __restrict__ k2,
             const float* __restrict__ b2, float* __restrict__ a2) {
  const int tid = threadIdx.x;
  const int ox  = tid & 63;                                    // 0..63
  const int cg16 = __builtin_amdgcn_readfirstlane((tid >> 6) * 16);  // wave-uniform co base
  const int oy  = blockIdx.x;                                  // 0..63
  const int b   = blockIdx.y;

  float acc[16];
#pragma unroll
  for (int co = 0; co < 16; ++co) acc[co] = b2[cg16 + co];

  for (int dy = 0; dy < 3; ++dy) {
    const int iy  = 2*oy + dy;
    const bool rok = iy < H1;
    const int iyc = rok ? iy : (H1-1);
    for (int dx = 0; dx < 3; ++dx) {
      const int ix  = 2*ox + dx;
      const bool ok = rok && (ix < H1);
      const int ixc = (ix < H1) ? ix : (H1-1);
      const float4* ip = (const float4*)(a1 + ((size_t)(b*H1 + iyc)*H1 + ixc)*C1);
      const float* wp = k2 + (size_t)((dy*3+dx)*C1)*C2 + cg16;  // [ci][co]
#pragma unroll
      for (int g = 0; g < 8; ++g) {
        float4 t = ip[g];
        if (!ok) t = make_float4(0.f,0.f,0.f,0.f);
#pragma unroll
        for (int cc = 0; cc < 4; ++cc) {
          const float vv = (cc==0) ? t.x : (cc==1) ? t.y : (cc==2) ? t.z : t.w;
          const float* wr = wp + (size_t)(g*4+cc)*C2;
#pragma unroll
          for (int co = 0; co < 16; ++co) acc[co] = fmaf(vv, wr[co], acc[co]);
        }
      }
    }
  }
  float* op = a2 + ((size_t)(b*H2 + oy)*H2 + ox)*C2 + cg16;
#pragma unroll
  for (int g = 0; g < 4; ++g) {
    float4 o;
    o.x = fmaxf(acc[4*g+0], 0.f);
    o.y = fmaxf(acc[4*g+1], 0.f);
    o.z = fmaxf(acc[4*g+2], 0.f);
    o.w = fmaxf(acc[4*g+3], 0.f);
    ((float4*)op)[g] = o;
  }
}

// ---------------------------------------------------------------- FC1 partial
// x = a2 flat [32, 262144]; w1 [262144, 128]. 1024 blocks, each owns a 256-k
// span. x chunk staged transposed in LDS (pad 36). Threads = [q 32 n-quads]
// [bo 8 b-quads]; acc = [4b][4n] = 16 regs -> no spill at the 64-VGPR budget.
// Per k: 1 coalesced w1 float4 + 1 broadcast LDS float4 + 16 FMA.
#define FC1_G   1024
#define KSPAN   (K_FLAT / FC1_G)   // 256

__global__ __launch_bounds__(256)
void fc1_partial_k(const float* __restrict__ a2, const float* __restrict__ w1,
                   float* __restrict__ partial) {
  __shared__ __align__(16) float xT[KSPAN*36];   // 36,864 B
  const int tid = threadIdx.x;
  const int q   = tid & 31;    // n-quad: n = 4q..4q+3
  const int bo  = tid >> 5;    // 0..7 : b = 4bo..4bo+3
  const int k0  = blockIdx.x * KSPAN;

  // stage x chunk transposed: xT[k][b]
  {
    const int lb  = tid >> 3;    // 0..31
    const int lkq = tid & 7;
#pragma unroll
    for (int j = 0; j < 8; ++j) {
      const int k4 = lkq*4 + j*32;
      float4 t = *(const float4*)(a2 + (size_t)lb*K_FLAT + k0 + k4);
      xT[(k4+0)*36 + lb] = t.x;
      xT[(k4+1)*36 + lb] = t.y;
      xT[(k4+2)*36 + lb] = t.z;
      xT[(k4+3)*36 + lb] = t.w;
    }
  }
  __syncthreads();

  float4 a0 = make_float4(0.f,0.f,0.f,0.f), a1v = a0, a2v = a0, a3v = a0;
#pragma unroll 4
  for (int k = 0; k < KSPAN; ++k) {
    const float4 w4 = *(const float4*)(w1 + (size_t)(k0 + k)*NHID + 4*q);
    const float4 xb = *(const float4*)&xT[k*36 + 4*bo];
    a0.x = fmaf(xb.x, w4.x, a0.x); a0.y = fmaf(xb.x, w4.y, a0.y);
    a0.z = fmaf(xb.x, w4.z, a0.z); a0.w = fmaf(xb.x, w4.w, a0.w);
    a1v.x = fmaf(xb.y, w4.x, a1v.x); a1v.y = fmaf(xb.y, w4.y, a1v.y);
    a1v.z = fmaf(xb.y, w4.z, a1v.z); a1v.w = fmaf(xb.y, w4.w, a1v.w);
    a2v.x = fmaf(xb.z, w4.x, a2v.x); a2v.y = fmaf(xb.z, w4.y, a2v.y);
    a2v.z = fmaf(xb.z, w4.z, a2v.z); a2v.w = fmaf(xb.z, w4.w, a2v.w);
    a3v.x = fmaf(xb.w, w4.x, a3v.x); a3v.y = fmaf(xb.w, w4.y, a3v.y);
    a3v.z = fmaf(xb.w, w4.z, a3v.z); a3v.w = fmaf(xb.w, w4.w, a3v.w);
  }

  float* pp = partial + (size_t)blockIdx.x*(NB*NHID) + 4*q;
  *(float4*)(pp + (4*bo+0)*NHID) = a0;
  *(float4*)(pp + (4*bo+1)*NHID) = a1v;
  *(float4*)(pp + (4*bo+2)*NHID) = a2v;
  *(float4*)(pp + (4*bo+3)*NHID) = a3v;
}

// ---------------------------------------------------------------- FC1 reduce stage 1: 1024 -> 8
__global__ __launch_bounds__(128)
void fc1_reduce1_k(const float* __restrict__ partial, float* __restrict__ partial2) {
  const int t  = blockIdx.x*128 + threadIdx.x;  // 0..4095
  const int gc = blockIdx.y;                    // 0..7
  float s = 0.f;
#pragma unroll 8
  for (int g = gc*128; g < gc*128+128; ++g) s += partial[(size_t)g*(NB*NHID) + t];
  partial2[(size_t)gc*(NB*NHID) + t] = s;
}

// ---------------------------------------------------------------- FC1 reduce stage 2 (+bias+ReLU)
__global__ __launch_bounds__(256)
void fc1_reduce2_k(const float* __restrict__ partial2, const float* __restrict__ d1,
                   float* __restrict__ h) {
  const int t = blockIdx.x*256 + threadIdx.x;  // 0..4095
  float s = 0.f;
#pragma unroll
  for (int gc = 0; gc < 8; ++gc) s += partial2[(size_t)gc*(NB*NHID) + t];
  h[t] = fmaxf(s + d1[t & (NHID-1)], 0.f);
}

// ---------------------------------------------------------------- theta = h @ w2 + d2
__global__ __launch_bounds__(192)
void theta_k(const float* __restrict__ h, const float* __restrict__ w2,
             const float* __restrict__ d2, float* __restrict__ theta) {
  const int t = threadIdx.x;
  if (t >= NB*6) return;
  const int b = t / 6, j = t % 6;
  float s = d2[j];
  for (int n = 0; n < NHID; ++n) s = fmaf(h[b*NHID + n], w2[n*6 + j], s);
  theta[t] = s;
}

// ---------------------------------------------------------------- grid sample (bilinear, zero pad)
__global__ __launch_bounds__(256)
void sample_k(const float* __restrict__ img, const float* __restrict__ theta,
              float* __restrict__ out) {
  const int x = threadIdx.x;
  const int y = blockIdx.x & (IN_H-1);
  const int b = blockIdx.x >> 8;
  const float* tp = theta + b*6;
  const float t0 = tp[0], t1 = tp[1], t2 = tp[2];
  const float t3 = tp[3], t4 = tp[4], t5 = tp[5];

  const float xs = (2.f*x + 1.f)*(1.f/IN_W) - 1.f;
  const float ys = (2.f*y + 1.f)*(1.f/IN_H) - 1.f;
  const float gx = fmaf(t0, xs, fmaf(t1, ys, t2));
  const float gy = fmaf(t3, xs, fmaf(t4, ys, t5));
  const float px = fmaf(gx + 1.f, 0.5f*IN_W, -0.5f);
  const float py = fmaf(gy + 1.f, 0.5f*IN_H, -0.5f);

  const float x0f = floorf(px), y0f = floorf(py);
  const int ix0 = (int)x0f, iy0 = (int)y0f;
  const float wx1 = px - x0f, wx0 = 1.f - wx1;
  const float wy1 = py - y0f, wy0 = 1.f - wy1;

  float r = 0.f, g = 0.f, bl = 0.f;
  const float* ib = img + (size_t)b*IN_H*IN_W*C0;

  auto tap = [&](int yi, int xi, float w) {
    const bool v = (xi >= 0) && (xi < IN_W) && (yi >= 0) && (yi < IN_H);
    const int xc = xi < 0 ? 0 : (xi > IN_W-1 ? IN_W-1 : xi);
    const int yc = yi < 0 ? 0 : (yi > IN_H-1 ? IN_H-1 : yi);
    const float* p = ib + ((size_t)yc*IN_W + xc)*C0;
    if (v) {
      r  = fmaf(w, p[0], r);
      g  = fmaf(w, p[1], g);
      bl = fmaf(w, p[2], bl);
    }
  };
  tap(iy0,   ix0,   wy0*wx0);
  tap(iy0,   ix0+1, wy0*wx1);
  tap(iy0+1, ix0,   wy1*wx0);
  tap(iy0+1, ix0+1, wy1*wx1);

  float* op = out + ((size_t)(b*IN_H + y)*IN_W + x)*C0;
  op[0] = r; op[1] = g; op[2] = bl;
}

// ---------------------------------------------------------------- launch
extern "C" void kernel_launch(void* const* d_in, const int* in_sizes, int n_in,
                              void* d_out, int out_size, void* d_ws, size_t ws_size,
                              hipStream_t stream) {
  const float* in = (const float*)d_in[0];
  const float* k1 = (const float*)d_in[1];
  const float* b1 = (const float*)d_in[2];
  const float* k2 = (const float*)d_in[3];
  const float* b2 = (const float*)d_in[4];
  const float* w1 = (const float*)d_in[5];
  const float* d1 = (const float*)d_in[6];
  const float* w2 = (const float*)d_in[7];
  const float* d2 = (const float*)d_in[8];
  float* out = (float*)d_out;
  float* ws  = (float*)d_ws;

  // ws layout (float offsets):
  //   a1       [16,777,216] @ 0
  //   a2       [ 8,388,608] @ 16,777,216
  //   -- after conv2, a1 region is dead and reused: --
  //   partial  [1024*4096 = 4,194,304] @ 0
  //   partial2 [8*4096    =    32,768] @ 4,194,304
  //   h        [4096]                  @ 4,227,072
  //   theta    [192]                   @ 4,231,168
  float* a1      = ws;
  float* a2      = ws + (size_t)16777216;
  float* partial = ws;
  float* part2   = ws + (size_t)4194304;
  float* h       = ws + (size_t)4227072;
  float* th      = ws + (size_t)4231168;

  hipLaunchKernelGGL(conv1_k,       dim3(128, 32), dim3(128), 0, stream, in, k1, b1, a1);
  hipLaunchKernelGGL(conv2_k,       dim3(64, 32),  dim3(256), 0, stream, a1, k2, b2, a2);
  hipLaunchKernelGGL(fc1_partial_k, dim3(FC1_G),   dim3(256), 0, stream, a2, w1, partial);
  hipLaunchKernelGGL(fc1_reduce1_k, dim3(32, 8),   dim3(128), 0, stream, partial, part2);
  hipLaunchKernelGGL(fc1_reduce2_k, dim3(16),      dim3(256), 0, stream, part2, d1, h);
  hipLaunchKernelGGL(theta_k,       dim3(1),       dim3(192), 0, stream, h, w2, d2, th);
  hipLaunchKernelGGL(sample_k,      dim3(NB*IN_H), dim3(256), 0, stream, in, th, out);
}